// Round 10
// baseline (76.274 us; speedup 1.0000x reference)
//
#include <hip/hip_runtime.h>
#include <hip/hip_bf16.h>

// N=8192 points, k=8 exact kNN -> mean |plane distance|.
// R10: MFMA-filtered exact kNN.
//   d2(r,c) = sq_r + sq_c - 2 p_r.q_c ; the dot term is matmul-shaped -> MFMA.
//   bf16 hi/lo split, K=32 slots carry explicit products (hh+hl+lh per dim)
//   plus sq_c (hi/lo paired with 1.0); error <= ~0.004 abs, covered by the
//   filter margin 0.02 + 2e-3*T. Survivors re-scored exactly in f32 ->
//   selection stays exact (same packed-key tie-break as R1-R9).
#define NPTS 8192
#define KNN 8
#define NBC 8             // col-slices
#define CPB 1024          // cols per mfma block
#define TPB 256

typedef __attribute__((ext_vector_type(8))) short bf16x8;
typedef __attribute__((ext_vector_type(4))) float f32x4;

__device__ __forceinline__ unsigned int bf16rne(float x) {
    unsigned int u = __float_as_uint(x);
    return (u + 0x7FFFu + ((u >> 16) & 1u)) >> 16;
}
__device__ __forceinline__ float bf2f(unsigned int h) { return __uint_as_float(h << 16); }

__device__ __forceinline__ void insert8(unsigned int (&best)[KNN], unsigned int key) {
#pragma unroll
    for (int t = 0; t < KNN; ++t) {
        const unsigned int lo = min(best[t], key);
        key = max(best[t], key);
        best[t] = lo;
    }
}

// Pack pts (x,y,z,sq), build B-fragments (per-col 2x uint4), zero out.
__global__ __launch_bounds__(256) void prep_kernel(const float* __restrict__ means,
                                                   float4* __restrict__ pts,
                                                   uint4* __restrict__ bfragB,
                                                   float* __restrict__ out) {
    const int i = blockIdx.x * 256 + threadIdx.x;
    if (i == 0) out[0] = 0.0f;
    const float x = means[3 * i + 0];
    const float y = means[3 * i + 1];
    const float z = means[3 * i + 2];
    const float sq = x * x + y * y + z * z;
    pts[i] = make_float4(x, y, z, sq);
    const unsigned int hx = bf16rne(x), lx = bf16rne(x - bf2f(hx));
    const unsigned int hy = bf16rne(y), ly = bf16rne(y - bf2f(hy));
    const unsigned int hz = bf16rne(z), lz = bf16rne(z - bf2f(hz));
    const unsigned int hs = bf16rne(sq), ls = bf16rne(sq - bf2f(hs));
    // B slots g0: [hx,lx,hx, hy,ly,hy, hz,lz]  g1: [hz,hs,ls, 0...]
    bfragB[i * 2 + 0] = make_uint4(hx | (lx << 16), hx | (hy << 16), ly | (hy << 16), hz | (lz << 16));
    bfragB[i * 2 + 1] = make_uint4(hz | (hs << 16), ls, 0u, 0u);
}

// T per point from 256 strided samples (wave-uniform scalar loads).
__global__ __launch_bounds__(256) void thresh_kernel(const float4* __restrict__ pts,
                                                     float* __restrict__ Tm_arr) {
    __shared__ unsigned int lds_k[4][64][KNN + 1];
    const int tid = threadIdx.x;
    const int l = tid & 63;
    const int wv = __builtin_amdgcn_readfirstlane(tid >> 6);
    const int pt = blockIdx.x * 64 + l;
    const float4 mp = pts[pt];
    const float mx2 = -2.0f * mp.x, my2 = -2.0f * mp.y, mz2 = -2.0f * mp.z;
    unsigned int best[KNN];
#pragma unroll
    for (int s = 0; s < KNN; ++s) best[s] = 0xFFFFFFFFu;
#pragma unroll 8
    for (int m = 0; m < 64; ++m) {
        const int col = (wv + 4 * m) * 32;  // uniform per wave -> s_load
        const float4 q = pts[col];
        const float d2 = fmaxf(fmaf(mx2, q.x, fmaf(my2, q.y, fmaf(mz2, q.z, mp.w + q.w))), 0.0f);
        unsigned int key = (__float_as_uint(d2) & 0xFFFFE000u) | (unsigned int)col;
        key = (col == pt) ? 0xFFFFFFFFu : key;
        insert8(best, key);
    }
#pragma unroll
    for (int s = 0; s < KNN; ++s) lds_k[wv][l][s] = best[s];
    for (int st = 1; st < 4; st <<= 1) {
        __syncthreads();
        if ((wv & (2 * st - 1)) == 0) {
#pragma unroll
            for (int s = 0; s < KNN; ++s) insert8(best, lds_k[wv + st][l][s]);
#pragma unroll
            for (int s = 0; s < KNN; ++s) lds_k[wv][l][s] = best[s];
        }
    }
    if (wv == 0) {
        const float Tf = __uint_as_float(best[7] & 0xFFFFE000u);
        Tm_arr[pt] = Tf + 0.02f + 2e-3f * Tf;  // covers trunc + mfma error
    }
}

// Per block: 64 rows x 1024 cols. MFMA filter -> bitmask -> in-block decode,
// exact re-score, per-row partial top-8 -> part[row][cbi][8].
__global__ __launch_bounds__(256) void mfma_knn(const float4* __restrict__ pts,
                                                const uint4* __restrict__ bfragB,
                                                const float* __restrict__ Tm_arr,
                                                unsigned int* __restrict__ part) {
    __shared__ uint4 lds_b[CPB * 2];              // 32 KB (flat [col*2+g])
    __shared__ unsigned int lds_bits[4][64][8];   // 8 KB
    const int tid = threadIdx.x;
    const int l = tid & 63;
    const int wv = __builtin_amdgcn_readfirstlane(tid >> 6);
    const int rp = blockIdx.x >> 3;
    const int cbi = blockIdx.x & 7;
    const int cb = cbi * CPB;
    {   // stage B frags: 2048 uint4, coalesced
        const uint4* __restrict__ src = bfragB + cb * 2;
#pragma unroll
        for (int k = 0; k < 8; ++k) lds_b[tid + 256 * k] = src[tid + 256 * k];
    }
    const int rbase = rp * 64 + wv * 16;
    const int arow = rbase + (l & 15);
    const int g = l >> 4;
    const float4 mp = pts[arow];
    const float ax = -2.0f * mp.x, ay = -2.0f * mp.y, az = -2.0f * mp.z;
    const unsigned int hax = bf16rne(ax), lax = bf16rne(ax - bf2f(hax));
    const unsigned int hay = bf16rne(ay), lay = bf16rne(ay - bf2f(hay));
    const unsigned int haz = bf16rne(az), laz = bf16rne(az - bf2f(haz));
    // A slots g0: [hax,hax,lax, hay,hay,lay, haz,haz]  g1: [laz,1,1, 0...]  g2,g3: 0
    uint4 au = make_uint4(0u, 0u, 0u, 0u);
    if (g == 0) au = make_uint4(hax | (hax << 16), lax | (hay << 16), hay | (lay << 16), haz | (haz << 16));
    if (g == 1) au = make_uint4(laz | (0x3F80u << 16), 0x3F80u, 0u, 0u);
    union { uint4 u; bf16x8 v; } A; A.u = au;
    float sqr[4], Tm[4];
#pragma unroll
    for (int r = 0; r < 4; ++r) {
        const int rr = rbase + g * 4 + r;   // C layout: row=(l>>4)*4+r, col=l&15
        sqr[r] = pts[rr].w;
        Tm[r] = Tm_arr[rr];
    }
    __syncthreads();
    unsigned int m[8];
#pragma unroll
    for (int k = 0; k < 8; ++k) m[k] = 0u;
    const int bidx = (l & 15) * 2 + g;
    const f32x4 zero = {0.0f, 0.0f, 0.0f, 0.0f};
#pragma unroll 2
    for (int ch = 0; ch < 2; ++ch) {
#pragma unroll
        for (int t2 = 0; t2 < 32; ++t2) {
            const int ct = ch * 32 + t2;
            uint4 bu = make_uint4(0u, 0u, 0u, 0u);
            if (g < 2) bu = lds_b[ct * 32 + bidx];  // 32 consecutive uint4 -> conflict-free
            union { uint4 u; bf16x8 v; } B; B.u = bu;
            const f32x4 acc = __builtin_amdgcn_mfma_f32_16x16x32_bf16(A.v, B.v, zero, 0, 0, 0);
#pragma unroll
            for (int r = 0; r < 4; ++r) {
                const float d2 = sqr[r] + acc[r];
                m[r * 2 + ch] = m[r * 2 + ch] * 2u + ((d2 <= Tm[r]) ? 1u : 0u);
            }
        }
    }
#pragma unroll
    for (int k = 0; k < 8; ++k) lds_bits[wv][l][k] = m[k];
    __syncthreads();
    // decode: lane handles row (l&15), col-classes 4*(l>>4)..+3
    unsigned int best[KNN];
#pragma unroll
    for (int s = 0; s < KNN; ++s) best[s] = 0xFFFFFFFFu;
    const int LR = l & 15;
    const int slb = (LR >> 2) * 16;
    const int wb = (LR & 3) * 2;
#pragma unroll
    for (int cc = 0; cc < 4; ++cc) {
        const int cl = (l >> 4) * 4 + cc;
        const int sl = slb + cl;
#pragma unroll
        for (int ch = 0; ch < 2; ++ch) {
            unsigned int w = lds_bits[wv][sl][wb + ch];
            while (w) {
                const int b = __ffs(w) - 1;
                w &= w - 1;
                const int ct2 = 31 - b;
                const int col = cb + (ch * 32 + ct2) * 16 + cl;
                const float4 q = pts[col];
                const float d2 = fmaxf(fmaf(ax, q.x, fmaf(ay, q.y, fmaf(az, q.z, mp.w + q.w))), 0.0f);
                unsigned int key = (__float_as_uint(d2) & 0xFFFFE000u) | (unsigned int)col;
                key = (col == arow) ? 0xFFFFFFFFu : key;
                insert8(best, key);
            }
        }
    }
    // merge the 4 lanes sharing this row (xor 16, then 32)
#pragma unroll
    for (int st = 16; st <= 32; st <<= 1) {
        unsigned int tk[KNN];
#pragma unroll
        for (int s = 0; s < KNN; ++s) tk[s] = __shfl_xor(best[s], st);
#pragma unroll
        for (int s = 0; s < KNN; ++s) insert8(best, tk[s]);
    }
    if (l < 16) {
        uint4* dst = (uint4*)(part + ((unsigned int)arow * 8u + (unsigned int)cbi) * 8u);
        dst[0] = make_uint4(best[0], best[1], best[2], best[3]);
        dst[1] = make_uint4(best[4], best[5], best[6], best[7]);
    }
}

// Merge 8 slice-partials per row, plane distance, reduce.
__global__ __launch_bounds__(256) void final_kernel(const float4* __restrict__ pts,
                                                    const float* __restrict__ normals,
                                                    const unsigned int* __restrict__ part,
                                                    float* __restrict__ out) {
    __shared__ float red[4];
    const int row = blockIdx.x * 256 + threadIdx.x;
    unsigned int best[KNN];
#pragma unroll
    for (int s = 0; s < KNN; ++s) best[s] = 0xFFFFFFFFu;
    const uint4* __restrict__ P = (const uint4*)(part + (unsigned int)row * 64u);
#pragma unroll
    for (int b = 0; b < 16; ++b) {
        const uint4 v = P[b];
        insert8(best, v.x); insert8(best, v.y); insert8(best, v.z); insert8(best, v.w);
    }
    const float4 mp = pts[row];
    const float nx = normals[3 * row + 0], ny = normals[3 * row + 1], nz = normals[3 * row + 2];
    float sum = 0.0f;
#pragma unroll
    for (int s = 0; s < KNN; ++s) {
        const int nbr = (int)(best[s] & 0x1FFFu);
        const float4 q = pts[nbr];
        sum += fabsf((q.x - mp.x) * nx + (q.y - mp.y) * ny + (q.z - mp.z) * nz);
    }
    float v = sum;
#pragma unroll
    for (int off = 32; off > 0; off >>= 1) v += __shfl_down(v, off);
    if ((threadIdx.x & 63) == 0) red[threadIdx.x >> 6] = v;
    __syncthreads();
    if (threadIdx.x == 0)
        atomicAdd(out, (red[0] + red[1] + red[2] + red[3]) * (1.0f / ((float)NPTS * (float)KNN)));
}

extern "C" void kernel_launch(void* const* d_in, const int* in_sizes, int n_in,
                              void* d_out, int out_size, void* d_ws, size_t ws_size,
                              hipStream_t stream) {
    const float* means = (const float*)d_in[0];
    const float* normals = (const float*)d_in[1];
    float* out = (float*)d_out;
    char* ws = (char*)d_ws;
    float4* pts = (float4*)ws;                              // 128 KB
    uint4* bfragB = (uint4*)(ws + 131072);                  // 256 KB
    float* Tm = (float*)(ws + 393216);                      // 32 KB
    unsigned int* part = (unsigned int*)(ws + 425984);      // 2 MB

    prep_kernel<<<NPTS / 256, 256, 0, stream>>>(means, pts, bfragB, out);
    thresh_kernel<<<NPTS / 64, 256, 0, stream>>>(pts, Tm);
    mfma_knn<<<(NPTS / 64) * NBC, 256, 0, stream>>>(pts, bfragB, Tm, part);
    final_kernel<<<NPTS / 256, 256, 0, stream>>>(pts, normals, part, out);
}

// Round 11
// 41.212 us; speedup vs baseline: 1.8508x; 1.8508x over previous
//
#include <hip/hip_runtime.h>
#include <hip/hip_bf16.h>

// N=8192 points, k=8 exact kNN -> mean |plane distance|.
// R11: MFMA-filtered exact kNN, execution fixed.
//   d2(r,c) = sq_r + sq_c - 2 p_r.q_c via 16x16x32 bf16 MFMA, hi/lo split:
//   K slots 0-7: hh/hl/lh products per dim; 8: laz*hz; 9,10: 1*(hs_c,ls_c);
//   11,12: (hs_r,ls_r)*1  -> acc = d2 estimate directly (err <~ 0.004 abs).
//   Margin 0.02+2e-3*T keeps the filter a guaranteed superset; survivors are
//   re-scored exactly in f32 -> selection exact (packed-key jax tie-break).
#define NPTS 8192
#define KNN 8
#define NBC 8             // col-slices per row-group
#define CPB 1024          // cols per mfma block

typedef __attribute__((ext_vector_type(8))) short bf16x8;
typedef __attribute__((ext_vector_type(4))) float f32x4;

__device__ __forceinline__ unsigned int bf16rne(float x) {
    unsigned int u = __float_as_uint(x);
    return (u + 0x7FFFu + ((u >> 16) & 1u)) >> 16;
}
__device__ __forceinline__ float bf2f(unsigned int h) { return __uint_as_float(h << 16); }

__device__ __forceinline__ void insert8(unsigned int (&best)[KNN], unsigned int key) {
#pragma unroll
    for (int t = 0; t < KNN; ++t) {
        const unsigned int lo = min(best[t], key);
        key = max(best[t], key);
        best[t] = lo;
    }
}

// One kernel: pack pts + B-fragments, zero out, and per-point threshold from
// 256 strided samples (wave-uniform scalar loads straight from means[]).
__global__ __launch_bounds__(256) void prep_thresh(const float* __restrict__ means,
                                                   float4* __restrict__ pts,
                                                   uint4* __restrict__ bfragB,
                                                   float* __restrict__ Tm_arr,
                                                   float* __restrict__ out) {
    __shared__ unsigned int lds_k[4][64][5];  // 4 keys/thread (+pad)
    const int tid = threadIdx.x;
    const int l = tid & 63;
    const int wv = __builtin_amdgcn_readfirstlane(tid >> 6);
    const int pt = blockIdx.x * 64 + l;
    if (blockIdx.x == 0 && tid == 0) out[0] = 0.0f;

    const float x = means[3 * pt + 0];
    const float y = means[3 * pt + 1];
    const float z = means[3 * pt + 2];
    const float sq = x * x + y * y + z * z;
    if (wv == 0) {
        pts[pt] = make_float4(x, y, z, sq);
        const unsigned int hx = bf16rne(x), lx = bf16rne(x - bf2f(hx));
        const unsigned int hy = bf16rne(y), ly = bf16rne(y - bf2f(hy));
        const unsigned int hz = bf16rne(z), lz = bf16rne(z - bf2f(hz));
        const unsigned int hs = bf16rne(sq), ls = bf16rne(sq - bf2f(hs));
        // B g0: [hx,lx,hx, hy,ly,hy, hz,lz]   g1: [hz, hs, ls, 1, 1, 0,0,0]
        bfragB[pt * 2 + 0] = make_uint4(hx | (lx << 16), hx | (hy << 16),
                                        ly | (hy << 16), hz | (lz << 16));
        bfragB[pt * 2 + 1] = make_uint4(hz | (hs << 16), ls | (0x3F80u << 16), 0x3F80u, 0u);
    }

    // 64 samples per thread, cols 32*(wv+4m): wave-uniform -> scalar loads
    const float mx2 = -2.0f * x, my2 = -2.0f * y, mz2 = -2.0f * z;
    unsigned int b4[4] = {0xFFFFFFFFu, 0xFFFFFFFFu, 0xFFFFFFFFu, 0xFFFFFFFFu};
#pragma unroll 4
    for (int m = 0; m < 64; ++m) {
        const int col = 32 * (wv + 4 * m);
        const float qx = means[3 * col + 0];
        const float qy = means[3 * col + 1];
        const float qz = means[3 * col + 2];
        const float qsq = qx * qx + qy * qy + qz * qz;
        const float d2 = fmaxf(fmaf(mx2, qx, fmaf(my2, qy, fmaf(mz2, qz, sq + qsq))), 0.0f);
        unsigned int key = (__float_as_uint(d2) & 0xFFFFE000u) | (unsigned int)col;
        key = (col == pt) ? 0xFFFFFFFFu : key;
#pragma unroll
        for (int t = 0; t < 4; ++t) {  // keep 4 smallest (subset -> valid bound)
            const unsigned int lo = min(b4[t], key);
            key = max(b4[t], key);
            b4[t] = lo;
        }
    }
#pragma unroll
    for (int s = 0; s < 4; ++s) lds_k[wv][l][s] = b4[s];
    __syncthreads();
    if (wv == 0) {
        unsigned int best[KNN] = {b4[0], b4[1], b4[2], b4[3],
                                  0xFFFFFFFFu, 0xFFFFFFFFu, 0xFFFFFFFFu, 0xFFFFFFFFu};
#pragma unroll
        for (int w = 1; w < 4; ++w)
#pragma unroll
            for (int s = 0; s < 4; ++s) insert8(best, lds_k[w][l][s]);
        const float Tf = __uint_as_float(best[7] & 0xFFFFE000u);
        Tm_arr[pt] = Tf + 0.02f + 2e-3f * Tf;  // covers trunc + mfma error
    }
}

// Per block: 64 rows x 1024 cols. MFMA filter -> bitmask -> in-block decode,
// exact re-score, per-row partial top-8 -> part[row][cbi][8].
__global__ __launch_bounds__(256) void mfma_knn(const float4* __restrict__ pts,
                                                const uint4* __restrict__ bfragB,
                                                const float* __restrict__ Tm_arr,
                                                unsigned int* __restrict__ part) {
    __shared__ uint4 lds_b[CPB * 2];              // 32 KB, flat [col*2 + kgrp]
    __shared__ unsigned int lds_bits[4][64][8];   // 8 KB
    const int tid = threadIdx.x;
    const int l = tid & 63;
    const int wv = __builtin_amdgcn_readfirstlane(tid >> 6);
    const int rp = blockIdx.x >> 3;
    const int cbi = blockIdx.x & 7;
    const int cb = cbi * CPB;
    {   // stage B frags: 2048 uint4, coalesced
        const uint4* __restrict__ src = bfragB + cb * 2;
#pragma unroll
        for (int k = 0; k < 8; ++k) lds_b[tid + 256 * k] = src[tid + 256 * k];
    }
    const int rbase = rp * 64 + wv * 16;
    const int arow = rbase + (l & 15);
    const int g = l >> 4;
    const float4 mp = pts[arow];
    const float ax = -2.0f * mp.x, ay = -2.0f * mp.y, az = -2.0f * mp.z;
    const unsigned int hax = bf16rne(ax), lax = bf16rne(ax - bf2f(hax));
    const unsigned int hay = bf16rne(ay), lay = bf16rne(ay - bf2f(hay));
    const unsigned int haz = bf16rne(az), laz = bf16rne(az - bf2f(haz));
    const unsigned int hsr = bf16rne(mp.w), lsr = bf16rne(mp.w - bf2f(hsr));
    // A g0: [hax,hax,lax, hay,hay,lay, haz,haz]  g1: [laz, 1, 1, hsr, lsr, 0,0,0]
    uint4 au = make_uint4(0u, 0u, 0u, 0u);
    if (g == 0) au = make_uint4(hax | (hax << 16), lax | (hay << 16),
                                hay | (lay << 16), haz | (haz << 16));
    if (g == 1) au = make_uint4(laz | (0x3F80u << 16), 0x3F80u | (hsr << 16), lsr, 0u);
    union { uint4 u; bf16x8 v; } A; A.u = au;
    float Tm[4];
#pragma unroll
    for (int r = 0; r < 4; ++r) Tm[r] = Tm_arr[rbase + g * 4 + r];  // C row = g*4+r
    __syncthreads();

    // lanes 32-63 read the same address as 0-31 (broadcast, free); their A is
    // zero in k16-31 so the duplicated B contributes nothing.
    const int bidx = (l & 15) * 2 + (g & 1);
    const f32x4 zero = {0.0f, 0.0f, 0.0f, 0.0f};
    unsigned int m0[4], m1[4];
#pragma unroll
    for (int r = 0; r < 4; ++r) { m0[r] = 0u; m1[r] = 0u; }
#pragma unroll 4
    for (int t2 = 0; t2 < 32; ++t2) {
        union { uint4 u; bf16x8 v; } B; B.u = lds_b[t2 * 32 + bidx];
        const f32x4 acc = __builtin_amdgcn_mfma_f32_16x16x32_bf16(A.v, B.v, zero, 0, 0, 0);
#pragma unroll
        for (int r = 0; r < 4; ++r) m0[r] = m0[r] * 2u + ((acc[r] <= Tm[r]) ? 1u : 0u);
    }
#pragma unroll 4
    for (int t2 = 0; t2 < 32; ++t2) {
        union { uint4 u; bf16x8 v; } B; B.u = lds_b[(32 + t2) * 32 + bidx];
        const f32x4 acc = __builtin_amdgcn_mfma_f32_16x16x32_bf16(A.v, B.v, zero, 0, 0, 0);
#pragma unroll
        for (int r = 0; r < 4; ++r) m1[r] = m1[r] * 2u + ((acc[r] <= Tm[r]) ? 1u : 0u);
    }
#pragma unroll
    for (int r = 0; r < 4; ++r) {
        lds_bits[wv][l][r * 2 + 0] = m0[r];
        lds_bits[wv][l][r * 2 + 1] = m1[r];
    }
    __syncthreads();

    // decode: lane handles row (l&15), col-classes 4*(l>>4)..+3
    unsigned int best[KNN];
#pragma unroll
    for (int s = 0; s < KNN; ++s) best[s] = 0xFFFFFFFFu;
    const int LR = l & 15;
    const int slb = (LR >> 2) * 16;
    const int wb = (LR & 3) * 2;
#pragma unroll
    for (int cc = 0; cc < 4; ++cc) {
        const int cl = (l >> 4) * 4 + cc;
        const int sl = slb + cl;
#pragma unroll
        for (int ch = 0; ch < 2; ++ch) {
            unsigned int w = lds_bits[wv][sl][wb + ch];
            while (w) {
                const int b = __ffs(w) - 1;
                w &= w - 1;
                const int ct2 = 31 - b;
                const int col = cb + (ch * 32 + ct2) * 16 + cl;
                const float4 q = pts[col];
                const float d2 = fmaxf(fmaf(ax, q.x, fmaf(ay, q.y, fmaf(az, q.z, mp.w + q.w))), 0.0f);
                unsigned int key = (__float_as_uint(d2) & 0xFFFFE000u) | (unsigned int)col;
                key = (col == arow) ? 0xFFFFFFFFu : key;
                insert8(best, key);
            }
        }
    }
    // merge the 4 lanes sharing this row (xor 16, then 32)
#pragma unroll
    for (int st = 16; st <= 32; st <<= 1) {
        unsigned int tk[KNN];
#pragma unroll
        for (int s = 0; s < KNN; ++s) tk[s] = __shfl_xor(best[s], st);
#pragma unroll
        for (int s = 0; s < KNN; ++s) insert8(best, tk[s]);
    }
    if (l < 16) {
        uint4* dst = (uint4*)(part + ((unsigned int)arow * 8u + (unsigned int)cbi) * 8u);
        dst[0] = make_uint4(best[0], best[1], best[2], best[3]);
        dst[1] = make_uint4(best[4], best[5], best[6], best[7]);
    }
}

// Merge 8 slice-partials per row, plane distance, reduce.
__global__ __launch_bounds__(256) void final_kernel(const float4* __restrict__ pts,
                                                    const float* __restrict__ normals,
                                                    const unsigned int* __restrict__ part,
                                                    float* __restrict__ out) {
    __shared__ float red[4];
    const int row = blockIdx.x * 256 + threadIdx.x;
    unsigned int best[KNN];
#pragma unroll
    for (int s = 0; s < KNN; ++s) best[s] = 0xFFFFFFFFu;
    const uint4* __restrict__ P = (const uint4*)(part + (unsigned int)row * 64u);
#pragma unroll
    for (int b = 0; b < 16; ++b) {
        const uint4 v = P[b];
        insert8(best, v.x); insert8(best, v.y); insert8(best, v.z); insert8(best, v.w);
    }
    const float4 mp = pts[row];
    const float nx = normals[3 * row + 0], ny = normals[3 * row + 1], nz = normals[3 * row + 2];
    float sum = 0.0f;
#pragma unroll
    for (int s = 0; s < KNN; ++s) {
        const int nbr = (int)(best[s] & 0x1FFFu);
        const float4 q = pts[nbr];
        sum += fabsf((q.x - mp.x) * nx + (q.y - mp.y) * ny + (q.z - mp.z) * nz);
    }
    float v = sum;
#pragma unroll
    for (int off = 32; off > 0; off >>= 1) v += __shfl_down(v, off);
    if ((threadIdx.x & 63) == 0) red[threadIdx.x >> 6] = v;
    __syncthreads();
    if (threadIdx.x == 0)
        atomicAdd(out, (red[0] + red[1] + red[2] + red[3]) * (1.0f / ((float)NPTS * (float)KNN)));
}

extern "C" void kernel_launch(void* const* d_in, const int* in_sizes, int n_in,
                              void* d_out, int out_size, void* d_ws, size_t ws_size,
                              hipStream_t stream) {
    const float* means = (const float*)d_in[0];
    const float* normals = (const float*)d_in[1];
    float* out = (float*)d_out;
    char* ws = (char*)d_ws;
    float4* pts = (float4*)ws;                              // 128 KB
    uint4* bfragB = (uint4*)(ws + 131072);                  // 256 KB
    float* Tm = (float*)(ws + 393216);                      // 32 KB
    unsigned int* part = (unsigned int*)(ws + 425984);      // 2 MB

    prep_thresh<<<NPTS / 64, 256, 0, stream>>>(means, pts, bfragB, Tm, out);
    mfma_knn<<<(NPTS / 64) * NBC, 256, 0, stream>>>(pts, bfragB, Tm, part);
    final_kernel<<<NPTS / 256, 256, 0, stream>>>(pts, normals, part, out);
}